// Round 3
// baseline (265.385 us; speedup 1.0000x reference)
//
#include <hip/hip_runtime.h>

#define NB 4
#define NS 2048
#define ND 768
#define NH 12
#define NDH 64
#define NM (NB * NS)   // 8192

typedef __attribute__((ext_vector_type(8))) _Float16 f16x8;
typedef __attribute__((ext_vector_type(4))) _Float16 f16x4;
typedef __attribute__((ext_vector_type(2))) _Float16 f16x2;
typedef __attribute__((ext_vector_type(8))) unsigned short u16x8;
typedef __attribute__((ext_vector_type(4))) unsigned short u16x4;
typedef __attribute__((ext_vector_type(4))) float f32x4;

__device__ __forceinline__ unsigned short f2h(float f) {
    _Float16 h = (_Float16)f;
    return __builtin_bit_cast(unsigned short, h);
}
__device__ __forceinline__ f16x8 ldf16x8(const unsigned short* p) {
    return __builtin_bit_cast(f16x8, *(const u16x8*)p);
}
__device__ __forceinline__ f16x4 ldf16x4(const unsigned short* p) {
    return __builtin_bit_cast(f16x4, *(const u16x4*)p);
}
__device__ __forceinline__ void gload_lds16(const void* g, void* l) {
    __builtin_amdgcn_global_load_lds(
        (const __attribute__((address_space(1))) void*)g,
        (__attribute__((address_space(3))) void*)l, 16, 0, 0);
}

// raw v_exp_f32: skips OCML wrapper; flush-to-zero is right for softmax tails.
__device__ __forceinline__ float exp2_fast(float x) {
#if __has_builtin(__builtin_amdgcn_exp2f)
    return __builtin_amdgcn_exp2f(x);
#else
    return exp2f(x);
#endif
}

// fmaxf triple — clang fuses to v_max3_f32
__device__ __forceinline__ float max3f(float a, float b, float c) {
    return fmaxf(fmaxf(a, b), c);
}

// packed f32 -> f16 pair (v_cvt_pkrtz_f16_f32)
__device__ __forceinline__ f16x4 pk4(float a, float b, float c, float d) {
#if __has_builtin(__builtin_amdgcn_cvt_pkrtz)
    f16x2 lo = __builtin_bit_cast(f16x2, __builtin_amdgcn_cvt_pkrtz(a, b));
    f16x2 hi = __builtin_bit_cast(f16x2, __builtin_amdgcn_cvt_pkrtz(c, d));
    f16x4 r;
    r[0] = lo[0]; r[1] = lo[1]; r[2] = hi[0]; r[3] = hi[1];
    return r;
#else
    f16x4 r;
    r[0] = (_Float16)a; r[1] = (_Float16)b;
    r[2] = (_Float16)c; r[3] = (_Float16)d;
    return r;
#endif
}

// ---------------------------------------------------------------------------
// Kernel 0: fp32 -> fp16 conversion of x, Wq, Wk, Wv into ws (xh | wh[3])
// ---------------------------------------------------------------------------
__global__ __launch_bounds__(256)
void conv_f32_to_f16(const float* __restrict__ x,
                     const float* __restrict__ wq,
                     const float* __restrict__ wk,
                     const float* __restrict__ wv,
                     unsigned short* __restrict__ dst)
{
    const int CX = (NM * ND) / 8;
    const int CW = (ND * ND) / 8;
    int c = blockIdx.x * 256 + threadIdx.x;
    const float* src;
    int base;
    if (c < CX)               { src = x;  base = 0; }
    else if (c < CX + CW)     { src = wq; base = CX; }
    else if (c < CX + 2 * CW) { src = wk; base = CX + CW; }
    else                      { src = wv; base = CX + 2 * CW; }
    const float4* p = (const float4*)&src[(size_t)(c - base) * 8];
    float4 a = p[0], b = p[1];
    u16x8 r;
    r[0] = f2h(a.x); r[1] = f2h(a.y); r[2] = f2h(a.z); r[3] = f2h(a.w);
    r[4] = f2h(b.x); r[5] = f2h(b.y); r[6] = f2h(b.z); r[7] = f2h(b.w);
    *(u16x8*)&dst[(size_t)c * 8] = r;
}

// ---------------------------------------------------------------------------
// Kernel 1: QKV GEMM, m97 structure (unchanged this round)
// ---------------------------------------------------------------------------
__global__ __launch_bounds__(256)
void qkv_gemm(const unsigned short* __restrict__ xh,
              const unsigned short* __restrict__ wh,
              const float* __restrict__ bq,
              const float* __restrict__ bk,
              const float* __restrict__ bv,
              unsigned short* __restrict__ qkv)
{
    const int z = blockIdx.z;
    const unsigned short* W = wh + (size_t)z * ND * ND;
    const float* bias = (z == 0) ? bq : (z == 1) ? bk : bv;
    unsigned short* out = qkv + (size_t)z * NM * ND;

    const int m0 = blockIdx.x * 128;
    const int n0 = blockIdx.y * 128;
    const int tid = threadIdx.x;
    const int lane = tid & 63, wave = tid >> 6;
    const int quad = lane >> 4, l16 = lane & 15;
    const int wm = (wave >> 1) * 64, wn = (wave & 1) * 64;

    __shared__ __align__(16) unsigned short As[128 * 32];
    __shared__ __align__(16) unsigned short Bs[128 * 32];

    const f32x4 fz = {0.f, 0.f, 0.f, 0.f};
    f32x4 acc[4][4];
#pragma unroll
    for (int i = 0; i < 4; ++i)
#pragma unroll
        for (int j = 0; j < 4; ++j) acc[i][j] = fz;

    const int lrow = lane >> 2;          // 0..15
    const int lcol = (lane & 3) * 8;     // 0,8,16,24

    for (int kt = 0; kt < ND / 32; ++kt) {
        const int k0 = kt * 32;
        __syncthreads();
#pragma unroll
        for (int i = 0; i < 2; ++i) {
            const int seg = wave * 2 + i;        // 0..7
            const int row = seg * 16 + lrow;
            gload_lds16(&xh[(size_t)(m0 + row) * ND + k0 + lcol], &As[seg * 512]);
            gload_lds16(&W[(size_t)(n0 + row) * ND + k0 + lcol], &Bs[seg * 512]);
        }
        __syncthreads();

        f16x8 af[4], bf_[4];
#pragma unroll
        for (int mi = 0; mi < 4; ++mi)
            af[mi] = ldf16x8(&As[(wm + mi * 16 + l16) * 32 + quad * 8]);
#pragma unroll
        for (int ni = 0; ni < 4; ++ni)
            bf_[ni] = ldf16x8(&Bs[(wn + ni * 16 + l16) * 32 + quad * 8]);
#pragma unroll
        for (int mi = 0; mi < 4; ++mi)
#pragma unroll
            for (int ni = 0; ni < 4; ++ni)
                acc[mi][ni] = __builtin_amdgcn_mfma_f32_16x16x32_f16(
                    af[mi], bf_[ni], acc[mi][ni], 0, 0, 0);
    }

#pragma unroll
    for (int ni = 0; ni < 4; ++ni) {
        const int n = n0 + wn + ni * 16 + l16;
        const float bval = bias[n];
        const int hh = n >> 6, d = n & 63;
#pragma unroll
        for (int mi = 0; mi < 4; ++mi) {
#pragma unroll
            for (int r = 0; r < 4; ++r) {
                const int m = m0 + wm + mi * 16 + quad * 4 + r;
                const int bi = m >> 11, s = m & (NS - 1);
                out[(((size_t)(bi * NH + hh)) * NS + s) * NDH + d] =
                    f2h(acc[mi][ni][r] + bval);
            }
        }
    }
}

// ---------------------------------------------------------------------------
// Kernel 2: flash attention via S^T = K Q^T.
// This round: K LDS tile DELETED — ak fragments loaded straight from global
// (fragment layout == global layout; all 4 waves hit the same 16KB tile in
// L1/L2), double-buffered akA/akB register prefetch. VTs stride 136->132
// (dword stride 66 === 2 mod 32 -> conflict-free b64 reads). max3 row-max.
// Keeps round-2 wins: raw v_exp, defer-max, partial lsum, cvt_pkrtz, setprio.
// ---------------------------------------------------------------------------
#define KLD 132   // VTs row stride: 128 kv + 4 pad (264B rows, 8B-aligned)

__global__ __launch_bounds__(256)
void attn_kernel(const unsigned short* __restrict__ qh,
                 const unsigned short* __restrict__ kh,
                 const unsigned short* __restrict__ vh,
                 float* __restrict__ out)
{
    const int bh = blockIdx.y;
    const int bb = bh / NH, hh = bh % NH;
    const int tid = threadIdx.x;
    const int lane = tid & 63, wave = tid >> 6;
    const int quad = lane >> 4, l16 = lane & 15;
    const int q0 = blockIdx.x * 128 + wave * 32;

    __shared__ __align__(16) unsigned short VTs[64 * KLD];   // [d][kv]

    const unsigned short* qb = qh + (size_t)bh * NS * NDH;
    const unsigned short* kb = kh + (size_t)bh * NS * NDH;
    const unsigned short* vb = vh + (size_t)bh * NS * NDH;

    // Q B-frags: B[n=q(l16)][k=dh(quad*8+j)]
    f16x8 bq_[2][2];
#pragma unroll
    for (int qt = 0; qt < 2; ++qt)
#pragma unroll
        for (int kk = 0; kk < 2; ++kk)
            bq_[qt][kk] = ldf16x8(
                &qb[(size_t)(q0 + qt * 16 + l16) * NDH + kk * 32 + quad * 8]);

    const float c2 = 0.18033688011112042f;  // log2(e) / sqrt(64)

    const f32x4 fz = {0.f, 0.f, 0.f, 0.f};
    f32x4 o[2][4];
    float m2[2], lsum[2];   // lsum is a per-lane PARTIAL (reduced in epilogue)
#pragma unroll
    for (int qt = 0; qt < 2; ++qt) {
#pragma unroll
        for (int dt = 0; dt < 4; ++dt) o[qt][dt] = fz;
        m2[qt] = -__builtin_inff();
        lsum[qt] = 0.f;
    }

    // ---- V staging geometry (unchanged) ----
    const int vpair = tid & 31;           // kv pair (+i2*32)
    const int vchunk = tid >> 5;          // 0..7 (d chunk)
    const unsigned short* vp = vb + (size_t)(2 * vpair) * NDH + vchunk * 8;

    u16x8 vr0[2], vr1[2];
#pragma unroll
    for (int i2 = 0; i2 < 2; ++i2) {
        vr0[i2] = *(const u16x8*)(vp + i2 * (64 * NDH));
        vr1[i2] = *(const u16x8*)(vp + i2 * (64 * NDH) + NDH);
    }

    // ---- K fragment base: global layout IS the A-frag layout ----
    // ak[kvt][kk] = K[kv0 + kvt*16 + l16][kk*32 + quad*8 .. +7]
    const unsigned short* kfp = kb + (size_t)l16 * NDH + quad * 8;
    const unsigned short* kcur = kfp;     // advances 128*NDH per tile

    f16x8 akA[4][2], akB[4][2];
    // prologue: tile 0, half 0
#pragma unroll
    for (int kvt = 0; kvt < 4; ++kvt)
#pragma unroll
        for (int kk = 0; kk < 2; ++kk)
            akA[kvt][kk] = ldf16x8(kcur + (kvt * 16) * NDH + kk * 32);

    // shared per-half compute body
    auto compute_half = [&](const f16x8 (&ak)[4][2], const int kvb) {
        // S^T = K · Q^T
        f32x4 st[2][4];
        __builtin_amdgcn_s_setprio(1);
#pragma unroll
        for (int qt = 0; qt < 2; ++qt)
#pragma unroll
            for (int kvt = 0; kvt < 4; ++kvt) {
                st[qt][kvt] = fz;
#pragma unroll
                for (int kk = 0; kk < 2; ++kk)
                    st[qt][kvt] = __builtin_amdgcn_mfma_f32_16x16x32_f16(
                        ak[kvt][kk], bq_[qt][kk], st[qt][kvt], 0, 0, 0);
            }
        __builtin_amdgcn_s_setprio(0);

        // V^T A-frags: A[m=d(l16)][k=kv(quad*4+j)]
        f16x4 av[4][4];
#pragma unroll
        for (int dt = 0; dt < 4; ++dt)
#pragma unroll
            for (int kvt = 0; kvt < 4; ++kvt)
                av[dt][kvt] = ldf16x4(
                    &VTs[(dt * 16 + l16) * KLD + kvb + kvt * 16 + quad * 4]);

        // online softmax (defer-max) + PV
#pragma unroll
        for (int qt = 0; qt < 2; ++qt) {
            // per-lane max over 16 S values via v_max3 tree (8 ops)
            const float r0 = max3f(st[qt][0][0], st[qt][0][1], st[qt][0][2]);
            const float r1 = max3f(st[qt][0][3], st[qt][1][0], st[qt][1][1]);
            const float r2 = max3f(st[qt][1][2], st[qt][1][3], st[qt][2][0]);
            const float r3 = max3f(st[qt][2][1], st[qt][2][2], st[qt][2][3]);
            const float r4 = max3f(st[qt][3][0], st[qt][3][1], st[qt][3][2]);
            float rm = fmaxf(max3f(r0, r1, r2), max3f(r3, r4, st[qt][3][3]));

            // defer-max: steady state skips shuffles, al-exp and rescale.
            if (!__all(rm * c2 <= m2[qt] + 8.f)) {
                rm = fmaxf(rm, __shfl_xor(rm, 16, 64));
                rm = fmaxf(rm, __shfl_xor(rm, 32, 64));
                const float mn = fmaxf(m2[qt], rm * c2);
                const float al = exp2_fast(m2[qt] - mn);
                m2[qt] = mn;
                lsum[qt] *= al;
#pragma unroll
                for (int dt = 0; dt < 4; ++dt)
                    o[qt][dt] *= al;
            }
            const float mn = m2[qt];

            float rs = 0.f;
            f16x4 pf[4];
#pragma unroll
            for (int kvt = 0; kvt < 4; ++kvt) {
                const float p0 = exp2_fast(fmaf(st[qt][kvt][0], c2, -mn));
                const float p1 = exp2_fast(fmaf(st[qt][kvt][1], c2, -mn));
                const float p2 = exp2_fast(fmaf(st[qt][kvt][2], c2, -mn));
                const float p3 = exp2_fast(fmaf(st[qt][kvt][3], c2, -mn));
                rs += (p0 + p1) + (p2 + p3);
                pf[kvt] = pk4(p0, p1, p2, p3);
            }
            lsum[qt] += rs;

            __builtin_amdgcn_s_setprio(1);
#pragma unroll
            for (int dt = 0; dt < 4; ++dt)
#pragma unroll
                for (int kvt = 0; kvt < 4; ++kvt)
                    o[qt][dt] = __builtin_amdgcn_mfma_f32_16x16x16f16(
                        av[dt][kvt], pf[kvt], o[qt][dt], 0, 0, 0);
            __builtin_amdgcn_s_setprio(0);
        }
    };

    const int NT = NS / 128;
    for (int kt = 0; kt < NT; ++kt) {
        __syncthreads();   // previous tile's VTs consumers done
        // ---- write staged V tile to LDS ----
#pragma unroll
        for (int i2 = 0; i2 < 2; ++i2) {
            const int P = vpair + i2 * 32;
#pragma unroll
            for (int j = 0; j < 8; ++j) {
                unsigned pk = (unsigned)vr0[i2][j] | ((unsigned)vr1[i2][j] << 16);
                *(unsigned*)&VTs[(vchunk * 8 + j) * KLD + 2 * P] = pk;
            }
        }
        // ---- prefetch next V tile (in flight during compute) ----
        vp += 128 * NDH;
        if (kt + 1 < NT) {
#pragma unroll
            for (int i2 = 0; i2 < 2; ++i2) {
                vr0[i2] = *(const u16x8*)(vp + i2 * (64 * NDH));
                vr1[i2] = *(const u16x8*)(vp + i2 * (64 * NDH) + NDH);
            }
        }
        __syncthreads();   // staged tile visible

        // ---- issue K loads for half 1 (cover under half-0 compute) ----
#pragma unroll
        for (int kvt = 0; kvt < 4; ++kvt)
#pragma unroll
            for (int kk = 0; kk < 2; ++kk)
                akB[kvt][kk] = ldf16x8(kcur + (64 + kvt * 16) * NDH + kk * 32);

        compute_half(akA, 0);

        // ---- issue K loads for next tile half 0 (cover under half-1) ----
        if (kt + 1 < NT) {
#pragma unroll
            for (int kvt = 0; kvt < 4; ++kvt)
#pragma unroll
                for (int kk = 0; kk < 2; ++kk)
                    akA[kvt][kk] = ldf16x8(kcur + (128 + kvt * 16) * NDH + kk * 32);
        }

        compute_half(akB, 64);

        kcur += 128 * NDH;
    }

    // epilogue: single cross-lane lsum reduce, then O^T C-layout -> out
#pragma unroll
    for (int qt = 0; qt < 2; ++qt) {
        const int q = q0 + qt * 16 + l16;
        float l = lsum[qt];
        l += __shfl_xor(l, 16, 64);
        l += __shfl_xor(l, 32, 64);
        const float inv = 1.f / l;
#pragma unroll
        for (int dt = 0; dt < 4; ++dt) {
            float4 v;
            v.x = o[qt][dt][0] * inv;
            v.y = o[qt][dt][1] * inv;
            v.z = o[qt][dt][2] * inv;
            v.w = o[qt][dt][3] * inv;
            *(float4*)&out[((size_t)(bb * NS + q)) * ND + hh * NDH + dt * 16 + quad * 4] = v;
        }
    }
}

// ---------------------------------------------------------------------------
extern "C" void kernel_launch(void* const* d_in, const int* in_sizes, int n_in,
                              void* d_out, int out_size, void* d_ws, size_t ws_size,
                              hipStream_t stream)
{
    const float* x  = (const float*)d_in[0];
    const float* Wq = (const float*)d_in[1];
    const float* bq = (const float*)d_in[2];
    const float* Wk = (const float*)d_in[3];
    const float* bk = (const float*)d_in[4];
    const float* Wv = (const float*)d_in[5];
    const float* bv = (const float*)d_in[6];

    unsigned short* ws  = (unsigned short*)d_ws;
    unsigned short* xh  = ws;                          // NM*ND f16
    unsigned short* wh  = xh + (size_t)NM * ND;        // 3*ND*ND f16
    unsigned short* qkv = wh + (size_t)3 * ND * ND;    // 3*NM*ND f16
    unsigned short* qhp = qkv;
    unsigned short* khp = qkv + (size_t)NM * ND;
    unsigned short* vhp = qkv + (size_t)2 * NM * ND;

    const int convBlocks = (NM * ND + 3 * ND * ND) / (8 * 256);
    conv_f32_to_f16<<<convBlocks, 256, 0, stream>>>(x, Wq, Wk, Wv, xh);

    qkv_gemm<<<dim3(NM / 128, ND / 128, 3), 256, 0, stream>>>(
        xh, wh, bq, bk, bv, qkv);

    attn_kernel<<<dim3(NS / 128, NB * NH), 256, 0, stream>>>(
        qhp, khp, vhp, (float*)d_out);
}

// Round 4
// 215.393 us; speedup vs baseline: 1.2321x; 1.2321x over previous
//
#include <hip/hip_runtime.h>

#define NB 4
#define NS 2048
#define ND 768
#define NH 12
#define NDH 64
#define NM (NB * NS)   // 8192

typedef __attribute__((ext_vector_type(8))) _Float16 f16x8;
typedef __attribute__((ext_vector_type(4))) _Float16 f16x4;
typedef __attribute__((ext_vector_type(2))) _Float16 f16x2;
typedef __attribute__((ext_vector_type(8))) unsigned short u16x8;
typedef __attribute__((ext_vector_type(4))) unsigned short u16x4;
typedef __attribute__((ext_vector_type(4))) float f32x4;

__device__ __forceinline__ unsigned short f2h(float f) {
    _Float16 h = (_Float16)f;
    return __builtin_bit_cast(unsigned short, h);
}
__device__ __forceinline__ f16x8 ldf16x8(const unsigned short* p) {
    return __builtin_bit_cast(f16x8, *(const u16x8*)p);
}
__device__ __forceinline__ f16x4 ldf16x4(const unsigned short* p) {
    return __builtin_bit_cast(f16x4, *(const u16x4*)p);
}
__device__ __forceinline__ void gload_lds16(const void* g, void* l) {
    __builtin_amdgcn_global_load_lds(
        (const __attribute__((address_space(1))) void*)g,
        (__attribute__((address_space(3))) void*)l, 16, 0, 0);
}

// raw v_exp_f32: skips OCML wrapper; flush-to-zero is right for softmax tails.
__device__ __forceinline__ float exp2_fast(float x) {
#if __has_builtin(__builtin_amdgcn_exp2f)
    return __builtin_amdgcn_exp2f(x);
#else
    return exp2f(x);
#endif
}

// fmaxf triple — clang fuses to v_max3_f32
__device__ __forceinline__ float max3f(float a, float b, float c) {
    return fmaxf(fmaxf(a, b), c);
}

// packed f32 -> f16 pair (v_cvt_pkrtz_f16_f32)
__device__ __forceinline__ f16x4 pk4(float a, float b, float c, float d) {
#if __has_builtin(__builtin_amdgcn_cvt_pkrtz)
    f16x2 lo = __builtin_bit_cast(f16x2, __builtin_amdgcn_cvt_pkrtz(a, b));
    f16x2 hi = __builtin_bit_cast(f16x2, __builtin_amdgcn_cvt_pkrtz(c, d));
    f16x4 r;
    r[0] = lo[0]; r[1] = lo[1]; r[2] = hi[0]; r[3] = hi[1];
    return r;
#else
    f16x4 r;
    r[0] = (_Float16)a; r[1] = (_Float16)b;
    r[2] = (_Float16)c; r[3] = (_Float16)d;
    return r;
#endif
}

// ---------------------------------------------------------------------------
// Kernel 0: fp32 -> fp16 conversion of x, Wq, Wk, Wv into ws (xh | wh[3])
// ---------------------------------------------------------------------------
__global__ __launch_bounds__(256)
void conv_f32_to_f16(const float* __restrict__ x,
                     const float* __restrict__ wq,
                     const float* __restrict__ wk,
                     const float* __restrict__ wv,
                     unsigned short* __restrict__ dst)
{
    const int CX = (NM * ND) / 8;
    const int CW = (ND * ND) / 8;
    int c = blockIdx.x * 256 + threadIdx.x;
    const float* src;
    int base;
    if (c < CX)               { src = x;  base = 0; }
    else if (c < CX + CW)     { src = wq; base = CX; }
    else if (c < CX + 2 * CW) { src = wk; base = CX + CW; }
    else                      { src = wv; base = CX + 2 * CW; }
    const float4* p = (const float4*)&src[(size_t)(c - base) * 8];
    float4 a = p[0], b = p[1];
    u16x8 r;
    r[0] = f2h(a.x); r[1] = f2h(a.y); r[2] = f2h(a.z); r[3] = f2h(a.w);
    r[4] = f2h(b.x); r[5] = f2h(b.y); r[6] = f2h(b.z); r[7] = f2h(b.w);
    *(u16x8*)&dst[(size_t)c * 8] = r;
}

// ---------------------------------------------------------------------------
// Kernel 1: QKV GEMM, m97 structure (unchanged this round)
// ---------------------------------------------------------------------------
__global__ __launch_bounds__(256)
void qkv_gemm(const unsigned short* __restrict__ xh,
              const unsigned short* __restrict__ wh,
              const float* __restrict__ bq,
              const float* __restrict__ bk,
              const float* __restrict__ bv,
              unsigned short* __restrict__ qkv)
{
    const int z = blockIdx.z;
    const unsigned short* W = wh + (size_t)z * ND * ND;
    const float* bias = (z == 0) ? bq : (z == 1) ? bk : bv;
    unsigned short* out = qkv + (size_t)z * NM * ND;

    const int m0 = blockIdx.x * 128;
    const int n0 = blockIdx.y * 128;
    const int tid = threadIdx.x;
    const int lane = tid & 63, wave = tid >> 6;
    const int quad = lane >> 4, l16 = lane & 15;
    const int wm = (wave >> 1) * 64, wn = (wave & 1) * 64;

    __shared__ __align__(16) unsigned short As[128 * 32];
    __shared__ __align__(16) unsigned short Bs[128 * 32];

    const f32x4 fz = {0.f, 0.f, 0.f, 0.f};
    f32x4 acc[4][4];
#pragma unroll
    for (int i = 0; i < 4; ++i)
#pragma unroll
        for (int j = 0; j < 4; ++j) acc[i][j] = fz;

    const int lrow = lane >> 2;          // 0..15
    const int lcol = (lane & 3) * 8;     // 0,8,16,24

    for (int kt = 0; kt < ND / 32; ++kt) {
        const int k0 = kt * 32;
        __syncthreads();
#pragma unroll
        for (int i = 0; i < 2; ++i) {
            const int seg = wave * 2 + i;        // 0..7
            const int row = seg * 16 + lrow;
            gload_lds16(&xh[(size_t)(m0 + row) * ND + k0 + lcol], &As[seg * 512]);
            gload_lds16(&W[(size_t)(n0 + row) * ND + k0 + lcol], &Bs[seg * 512]);
        }
        __syncthreads();

        f16x8 af[4], bf_[4];
#pragma unroll
        for (int mi = 0; mi < 4; ++mi)
            af[mi] = ldf16x8(&As[(wm + mi * 16 + l16) * 32 + quad * 8]);
#pragma unroll
        for (int ni = 0; ni < 4; ++ni)
            bf_[ni] = ldf16x8(&Bs[(wn + ni * 16 + l16) * 32 + quad * 8]);
#pragma unroll
        for (int mi = 0; mi < 4; ++mi)
#pragma unroll
            for (int ni = 0; ni < 4; ++ni)
                acc[mi][ni] = __builtin_amdgcn_mfma_f32_16x16x32_f16(
                    af[mi], bf_[ni], acc[mi][ni], 0, 0, 0);
    }

#pragma unroll
    for (int ni = 0; ni < 4; ++ni) {
        const int n = n0 + wn + ni * 16 + l16;
        const float bval = bias[n];
        const int hh = n >> 6, d = n & 63;
#pragma unroll
        for (int mi = 0; mi < 4; ++mi) {
#pragma unroll
            for (int r = 0; r < 4; ++r) {
                const int m = m0 + wm + mi * 16 + quad * 4 + r;
                const int bi = m >> 11, s = m & (NS - 1);
                out[(((size_t)(bi * NH + hh)) * NS + s) * NDH + d] =
                    f2h(acc[mi][ni][r] + bval);
            }
        }
    }
}

// ---------------------------------------------------------------------------
// Kernel 2: flash attention via S^T = K Q^T.
// Round-2 structure restored (K staged in LDS via register prefetch — the
// 107 us proven shape), with the conflict fix done RIGHT this time:
//   Ks: unpadded [128][64] + T2 XOR swizzle  col_half ^= (row&7)<<3
//       (guide §6 G4 / m214: pad does NOT fix this pattern, XOR does;
//        bank math: write slots (tid&7)^(tid>>3&7), read slots
//        (kk*4+quad)^(l16&7) — both exactly minimum, zero excess cycles)
//   VTs: KLD 132 (proven zero-conflict in round 3)
// Keeps all validated VALU wins: raw v_exp, defer-max, partial lsum,
// cvt_pkrtz, setprio, max3 row-max, pointer-increment prefetch.
// ---------------------------------------------------------------------------
#define KLD 132   // VTs row stride: 128 kv + 4 pad

__global__ __launch_bounds__(256)
void attn_kernel(const unsigned short* __restrict__ qh,
                 const unsigned short* __restrict__ kh,
                 const unsigned short* __restrict__ vh,
                 float* __restrict__ out)
{
    const int bh = blockIdx.y;
    const int bb = bh / NH, hh = bh % NH;
    const int tid = threadIdx.x;
    const int lane = tid & 63, wave = tid >> 6;
    const int quad = lane >> 4, l16 = lane & 15;
    const int q0 = blockIdx.x * 128 + wave * 32;

    __shared__ __align__(16) unsigned short Ks[128 * 64];    // [kv][dh] swizzled
    __shared__ __align__(16) unsigned short VTs[64 * KLD];   // [d][kv]

    const unsigned short* qb = qh + (size_t)bh * NS * NDH;
    const unsigned short* kb = kh + (size_t)bh * NS * NDH;
    const unsigned short* vb = vh + (size_t)bh * NS * NDH;

    // Q B-frags: B[n=q(l16)][k=dh(quad*8+j)]
    f16x8 bq_[2][2];
#pragma unroll
    for (int qt = 0; qt < 2; ++qt)
#pragma unroll
        for (int kk = 0; kk < 2; ++kk)
            bq_[qt][kk] = ldf16x8(
                &qb[(size_t)(q0 + qt * 16 + l16) * NDH + kk * 32 + quad * 8]);

    const float c2 = 0.18033688011112042f;  // log2(e) / sqrt(64)

    const f32x4 fz = {0.f, 0.f, 0.f, 0.f};
    f32x4 o[2][4];
    float m2[2], lsum[2];   // lsum is a per-lane PARTIAL (reduced in epilogue)
#pragma unroll
    for (int qt = 0; qt < 2; ++qt) {
#pragma unroll
        for (int dt = 0; dt < 4; ++dt) o[qt][dt] = fz;
        m2[qt] = -__builtin_inff();
        lsum[qt] = 0.f;
    }

    // staging geometry
    const int krow = tid >> 3;                       // 0..31 (K rows +i*32)
    const int kcol = (tid & 7) * 8;                  // global dh chunk (halves)
    const int kcolS = 8 * ((tid & 7) ^ (krow & 7));  // swizzled LDS col (halves)
    const int vpair = tid & 31;                      // kv pair (+i2*32)
    const int vchunk = tid >> 5;                     // 0..7 (d chunk)

    // ak read swizzle: row&7 == l16&7 (kvb, kvt*16 are multiples of 8)
    const int rdsw = (l16 & 7) << 3;

    // pointer-increment prefetch bases (no per-tile 64-bit muls)
    const unsigned short* kp = kb + (size_t)krow * NDH + kcol;
    const unsigned short* vp = vb + (size_t)(2 * vpair) * NDH + vchunk * 8;

    // prefetch registers (tile t+1 loads overlap tile t compute)
    u16x8 kr[4], vr0[2], vr1[2];
#pragma unroll
    for (int i = 0; i < 4; ++i)
        kr[i] = *(const u16x8*)(kp + i * (32 * NDH));
#pragma unroll
    for (int i2 = 0; i2 < 2; ++i2) {
        vr0[i2] = *(const u16x8*)(vp + i2 * (64 * NDH));
        vr1[i2] = *(const u16x8*)(vp + i2 * (64 * NDH) + NDH);
    }

    const int NT = NS / 128;
    for (int kt = 0; kt < NT; ++kt) {
        __syncthreads();   // previous tile's LDS consumers done
        // ---- write staged tile to LDS (Ks dest XOR-swizzled) ----
#pragma unroll
        for (int i = 0; i < 4; ++i)
            *(u16x8*)&Ks[(krow + i * 32) * 64 + kcolS] = kr[i];
#pragma unroll
        for (int i2 = 0; i2 < 2; ++i2) {
            const int P = vpair + i2 * 32;
#pragma unroll
            for (int j = 0; j < 8; ++j) {
                unsigned pk = (unsigned)vr0[i2][j] | ((unsigned)vr1[i2][j] << 16);
                *(unsigned*)&VTs[(vchunk * 8 + j) * KLD + 2 * P] = pk;
            }
        }
        // ---- prefetch next tile (in flight during compute) ----
        kp += 128 * NDH;
        vp += 128 * NDH;
        if (kt + 1 < NT) {
#pragma unroll
            for (int i = 0; i < 4; ++i)
                kr[i] = *(const u16x8*)(kp + i * (32 * NDH));
#pragma unroll
            for (int i2 = 0; i2 < 2; ++i2) {
                vr0[i2] = *(const u16x8*)(vp + i2 * (64 * NDH));
                vr1[i2] = *(const u16x8*)(vp + i2 * (64 * NDH) + NDH);
            }
        }
        __syncthreads();   // staged tile visible

        // ---- two 64-kv compute sub-tiles ----
#pragma unroll
        for (int half = 0; half < 2; ++half) {
            const int kvb = half * 64;

            // K A-frags: A[m=kv(l16)][k=dh(quad*8+j)], swizzled read
            f16x8 ak[4][2];
#pragma unroll
            for (int kvt = 0; kvt < 4; ++kvt)
#pragma unroll
                for (int kk = 0; kk < 2; ++kk)
                    ak[kvt][kk] = ldf16x8(
                        &Ks[(kvb + kvt * 16 + l16) * 64 +
                            ((kk * 32 + quad * 8) ^ rdsw)]);

            // S^T = K · Q^T
            f32x4 st[2][4];
            __builtin_amdgcn_s_setprio(1);
#pragma unroll
            for (int qt = 0; qt < 2; ++qt)
#pragma unroll
                for (int kvt = 0; kvt < 4; ++kvt) {
                    st[qt][kvt] = fz;
#pragma unroll
                    for (int kk = 0; kk < 2; ++kk)
                        st[qt][kvt] = __builtin_amdgcn_mfma_f32_16x16x32_f16(
                            ak[kvt][kk], bq_[qt][kk], st[qt][kvt], 0, 0, 0);
                }
            __builtin_amdgcn_s_setprio(0);

            // V^T A-frags: A[m=d(l16)][k=kv(quad*4+j)]
            f16x4 av[4][4];
#pragma unroll
            for (int dt = 0; dt < 4; ++dt)
#pragma unroll
                for (int kvt = 0; kvt < 4; ++kvt)
                    av[dt][kvt] = ldf16x4(
                        &VTs[(dt * 16 + l16) * KLD + kvb + kvt * 16 + quad * 4]);

            // online softmax (defer-max) + PV
#pragma unroll
            for (int qt = 0; qt < 2; ++qt) {
                // per-lane max over 16 S values via v_max3 tree
                const float r0 = max3f(st[qt][0][0], st[qt][0][1], st[qt][0][2]);
                const float r1 = max3f(st[qt][0][3], st[qt][1][0], st[qt][1][1]);
                const float r2 = max3f(st[qt][1][2], st[qt][1][3], st[qt][2][0]);
                const float r3 = max3f(st[qt][2][1], st[qt][2][2], st[qt][2][3]);
                const float r4 = max3f(st[qt][3][0], st[qt][3][1], st[qt][3][2]);
                float rm = fmaxf(max3f(r0, r1, r2), max3f(r3, r4, st[qt][3][3]));

                // defer-max: steady state skips shuffles, al-exp and rescale.
                if (!__all(rm * c2 <= m2[qt] + 8.f)) {
                    rm = fmaxf(rm, __shfl_xor(rm, 16, 64));
                    rm = fmaxf(rm, __shfl_xor(rm, 32, 64));
                    const float mn = fmaxf(m2[qt], rm * c2);
                    const float al = exp2_fast(m2[qt] - mn);
                    m2[qt] = mn;
                    lsum[qt] *= al;
#pragma unroll
                    for (int dt = 0; dt < 4; ++dt)
                        o[qt][dt] *= al;
                }
                const float mn = m2[qt];

                float rs = 0.f;
                f16x4 pf[4];
#pragma unroll
                for (int kvt = 0; kvt < 4; ++kvt) {
                    const float p0 = exp2_fast(fmaf(st[qt][kvt][0], c2, -mn));
                    const float p1 = exp2_fast(fmaf(st[qt][kvt][1], c2, -mn));
                    const float p2 = exp2_fast(fmaf(st[qt][kvt][2], c2, -mn));
                    const float p3 = exp2_fast(fmaf(st[qt][kvt][3], c2, -mn));
                    rs += (p0 + p1) + (p2 + p3);
                    pf[kvt] = pk4(p0, p1, p2, p3);
                }
                lsum[qt] += rs;   // per-lane partial; reduced once in epilogue

                __builtin_amdgcn_s_setprio(1);
#pragma unroll
                for (int dt = 0; dt < 4; ++dt)
#pragma unroll
                    for (int kvt = 0; kvt < 4; ++kvt)
                        o[qt][dt] = __builtin_amdgcn_mfma_f32_16x16x16f16(
                            av[dt][kvt], pf[kvt], o[qt][dt], 0, 0, 0);
                __builtin_amdgcn_s_setprio(0);
            }
        }
    }

    // epilogue: single cross-lane lsum reduce, then O^T C-layout -> out
#pragma unroll
    for (int qt = 0; qt < 2; ++qt) {
        const int q = q0 + qt * 16 + l16;
        float l = lsum[qt];
        l += __shfl_xor(l, 16, 64);
        l += __shfl_xor(l, 32, 64);
        const float inv = 1.f / l;
#pragma unroll
        for (int dt = 0; dt < 4; ++dt) {
            float4 v;
            v.x = o[qt][dt][0] * inv;
            v.y = o[qt][dt][1] * inv;
            v.z = o[qt][dt][2] * inv;
            v.w = o[qt][dt][3] * inv;
            *(float4*)&out[((size_t)(bb * NS + q)) * ND + hh * NDH + dt * 16 + quad * 4] = v;
        }
    }
}

// ---------------------------------------------------------------------------
extern "C" void kernel_launch(void* const* d_in, const int* in_sizes, int n_in,
                              void* d_out, int out_size, void* d_ws, size_t ws_size,
                              hipStream_t stream)
{
    const float* x  = (const float*)d_in[0];
    const float* Wq = (const float*)d_in[1];
    const float* bq = (const float*)d_in[2];
    const float* Wk = (const float*)d_in[3];
    const float* bk = (const float*)d_in[4];
    const float* Wv = (const float*)d_in[5];
    const float* bv = (const float*)d_in[6];

    unsigned short* ws  = (unsigned short*)d_ws;
    unsigned short* xh  = ws;                          // NM*ND f16
    unsigned short* wh  = xh + (size_t)NM * ND;        // 3*ND*ND f16
    unsigned short* qkv = wh + (size_t)3 * ND * ND;    // 3*NM*ND f16
    unsigned short* qhp = qkv;
    unsigned short* khp = qkv + (size_t)NM * ND;
    unsigned short* vhp = qkv + (size_t)2 * NM * ND;

    const int convBlocks = (NM * ND + 3 * ND * ND) / (8 * 256);
    conv_f32_to_f16<<<convBlocks, 256, 0, stream>>>(x, Wq, Wk, Wv, xh);

    qkv_gemm<<<dim3(NM / 128, ND / 128, 3), 256, 0, stream>>>(
        xh, wh, bq, bk, bv, qkv);

    attn_kernel<<<dim3(NS / 128, NB * NH), 256, 0, stream>>>(
        qhp, khp, vhp, (float*)d_out);
}